// Round 1
// baseline (1742.318 us; speedup 1.0000x reference)
//
#include <hip/hip_runtime.h>
#include <hip/hip_bf16.h>

#define N_NODES 50000
#define N_EDGES 800000
#define IN_DIM 128
#define F_SIZE 64
#define N_GRAPHS 512
#define OUT_DIM 10

// ---------------- utility ----------------
__global__ void k_fill(float* __restrict__ p, float v, long n) {
    long i = (long)blockIdx.x * blockDim.x + threadIdx.x;
    long stride = (long)gridDim.x * blockDim.x;
    for (; i < n; i += stride) p[i] = v;
}

// deg[i] starts at 1.0 (self loop); add 1 per edge targeting col=ind1[e]
__global__ void k_deg(const int* __restrict__ ind1, float* __restrict__ deg) {
    int e = blockIdx.x * blockDim.x + threadIdx.x;
    if (e < N_EDGES) atomicAdd(&deg[ind1[e]], 1.0f);
}

__global__ void k_rsqrt(float* __restrict__ deg) {
    int i = blockIdx.x * blockDim.x + threadIdx.x;
    if (i < N_NODES) deg[i] = rsqrtf(deg[i]);   // deg >= 1 always
}

// ---------------- Chebyshev SpMM: dst[ind0[e]] += v[e] * src[ind1[e]] (128 feats) ----------------
__global__ void k_spmm(const int* __restrict__ ind0, const int* __restrict__ ind1,
                       const float* __restrict__ vals,
                       const float* __restrict__ src, float* __restrict__ dst) {
    int t = blockIdx.x * blockDim.x + threadIdx.x;
    int e = t >> 6;
    int lane = t & 63;
    if (e >= N_EDGES) return;
    float v = vals[e];
    const float* s = src + (size_t)ind1[e] * IN_DIM;
    float* d = dst + (size_t)ind0[e] * IN_DIM;
    atomicAdd(&d[lane], v * s[lane]);
    atomicAdd(&d[lane + 64], v * s[lane + 64]);
}

// T2 = 2*T2 - X   (elementwise over N_NODES*IN_DIM)
__global__ void k_t2_finish(float* __restrict__ T2, const float* __restrict__ X) {
    long i = (long)blockIdx.x * blockDim.x + threadIdx.x;
    long n = (long)N_NODES * IN_DIM;
    long stride = (long)gridDim.x * blockDim.x;
    for (; i < n; i += stride) T2[i] = 2.0f * T2[i] - X[i];
}

// ---------------- GEMM: h = [X|T1|T2] @ W1  ([N,384]x[384,64]) ----------------
__global__ void k_gemm1(const float* __restrict__ X, const float* __restrict__ T1,
                        const float* __restrict__ T2, const float* __restrict__ W1,
                        float* __restrict__ h) {
    int c  = threadIdx.x & 63;
    int ry = threadIdx.x >> 6;
    int r  = blockIdx.x * 4 + ry;
    if (r >= N_NODES) return;
    const float* xr  = X  + (size_t)r * IN_DIM;
    const float* t1r = T1 + (size_t)r * IN_DIM;
    const float* t2r = T2 + (size_t)r * IN_DIM;
    float acc = 0.f;
    #pragma unroll 4
    for (int k = 0; k < 128; ++k) acc += xr[k]  * W1[(k)       * 64 + c];
    #pragma unroll 4
    for (int k = 0; k < 128; ++k) acc += t1r[k] * W1[(128 + k) * 64 + c];
    #pragma unroll 4
    for (int k = 0; k < 128; ++k) acc += t2r[k] * W1[(256 + k) * 64 + c];
    h[(size_t)r * 64 + c] = acc;
}

// h = x @ W  ([N,64]x[64,64])
__global__ void k_gemm64(const float* __restrict__ x, const float* __restrict__ W,
                         float* __restrict__ h) {
    int c  = threadIdx.x & 63;
    int ry = threadIdx.x >> 6;
    int r  = blockIdx.x * 4 + ry;
    if (r >= N_NODES) return;
    const float* xr = x + (size_t)r * 64;
    float acc = 0.f;
    #pragma unroll 8
    for (int k = 0; k < 64; ++k) acc += xr[k] * W[k * 64 + c];
    h[(size_t)r * 64 + c] = acc;
}

// ---------------- GCN conv scatter: acc[ind1[e]] += dis[r]*dis[c]*h[ind0[e]] ----------------
__global__ void k_conv(const int* __restrict__ ind0, const int* __restrict__ ind1,
                       const float* __restrict__ dis, const float* __restrict__ h,
                       float* __restrict__ acc) {
    int t = blockIdx.x * blockDim.x + threadIdx.x;
    int e = t >> 6;
    int f = t & 63;
    if (e >= N_EDGES) return;
    int r = ind0[e], c = ind1[e];
    float nw = dis[r] * dis[c];
    atomicAdd(&acc[(size_t)c * 64 + f], nw * h[(size_t)r * 64 + f]);
}

// x = relu(acc + dis[i]^2 * h[i] + b)
__global__ void k_conv_finish(const float* __restrict__ acc, const float* __restrict__ h,
                              const float* __restrict__ dis, const float* __restrict__ b,
                              float* __restrict__ x) {
    int t = blockIdx.x * blockDim.x + threadIdx.x;
    int i = t >> 6;
    int f = t & 63;
    if (i >= N_NODES) return;
    float d = dis[i];
    float v = acc[(size_t)i * 64 + f] + d * d * h[(size_t)i * 64 + f] + b[f];
    x[(size_t)i * 64 + f] = fmaxf(v, 0.f);
}

// ---------------- mean pool ----------------
__global__ void k_pool(const float* __restrict__ x1, const float* __restrict__ x2,
                       const float* __restrict__ x3, const int* __restrict__ batch,
                       float* __restrict__ pooled, float* __restrict__ counts) {
    int t = blockIdx.x * blockDim.x + threadIdx.x;
    int i = t >> 6;
    int f = t & 63;
    if (i >= N_NODES) return;
    int g = batch[i];
    size_t idx = (size_t)i * 64 + f;
    float xm = (x1[idx] + x2[idx] + x3[idx]) * (1.0f / 3.0f);
    atomicAdd(&pooled[(size_t)g * 64 + f], xm);
    if (f == 0) atomicAdd(&counts[g], 1.0f);
}

// ---------------- output head: softmax(pooled/cnt @ Wout + bout) ----------------
__global__ void k_out(const float* __restrict__ pooled, const float* __restrict__ counts,
                      const float* __restrict__ Wout, const float* __restrict__ bout,
                      float* __restrict__ out) {
    __shared__ float sh[64];
    __shared__ float logits[OUT_DIM];
    int g = blockIdx.x;
    int f = threadIdx.x;   // 64 threads
    float cnt = fmaxf(counts[g], 1.0f);
    sh[f] = pooled[(size_t)g * 64 + f] / cnt;
    __syncthreads();
    if (f < OUT_DIM) {
        float a = bout[f];
        for (int k = 0; k < 64; ++k) a += sh[k] * Wout[k * OUT_DIM + f];
        logits[f] = a;
    }
    __syncthreads();
    if (f < OUT_DIM) {
        float m = logits[0];
        for (int k = 1; k < OUT_DIM; ++k) m = fmaxf(m, logits[k]);
        float s = 0.f;
        for (int k = 0; k < OUT_DIM; ++k) s += expf(logits[k] - m);
        out[(size_t)g * OUT_DIM + f] = expf(logits[f] - m) / s;
    }
}

extern "C" void kernel_launch(void* const* d_in, const int* in_sizes, int n_in,
                              void* d_out, int out_size, void* d_ws, size_t ws_size,
                              hipStream_t stream) {
    const float* X     = (const float*)d_in[0];
    const int*   Lind  = (const int*)d_in[1];
    const int*   ind0  = Lind;              // indices[0]: scatter target of spmm / gather src of conv
    const int*   ind1  = Lind + N_EDGES;    // indices[1]: gather src of spmm / scatter target of conv
    const float* vals  = (const float*)d_in[2];
    const int*   batch = (const int*)d_in[3];
    const float* W1    = (const float*)d_in[4];
    const float* b1    = (const float*)d_in[5];
    const float* W2    = (const float*)d_in[6];
    const float* b2    = (const float*)d_in[7];
    const float* W3    = (const float*)d_in[8];
    const float* b3    = (const float*)d_in[9];
    const float* Wout  = (const float*)d_in[10];
    const float* bout  = (const float*)d_in[11];
    float* out = (float*)d_out;

    float* ws = (float*)d_ws;
    float* dis    = ws;                         // 50176
    float* T1     = ws + 50176;                 // 6,400,000
    float* T2     = T1 + 6400000;               // 6,400,000
    float* h      = T2 + 6400000;               // 3,200,000
    float* acc    = h  + 3200000;               // 3,200,000
    float* x1     = acc + 3200000;              // 3,200,000
    float* x2     = x1 + 3200000;
    float* x3     = x2 + 3200000;
    float* pooled = x3 + 3200000;               // 32768
    float* counts = pooled + N_GRAPHS * 64;     // 512

    const int B = 256;
    const int edgeGrid = (N_EDGES * 64) / B;        // 200000
    const int nodeGrid = (N_NODES * 64 + B - 1) / B;
    const int rowGrid  = (N_NODES + 3) / 4;

    // init: deg=1.0, zeros elsewhere
    k_fill<<<2048, B, 0, stream>>>(dis, 1.0f, N_NODES);
    k_fill<<<2048, B, 0, stream>>>(T1, 0.0f, (long)2 * 6400000);          // T1,T2 contiguous
    k_fill<<<64,   B, 0, stream>>>(pooled, 0.0f, N_GRAPHS * 64 + N_GRAPHS);

    // degree + normalization
    k_deg<<<(N_EDGES + B - 1) / B, B, 0, stream>>>(ind1, dis);
    k_rsqrt<<<(N_NODES + B - 1) / B, B, 0, stream>>>(dis);

    // Chebyshev: T1 = L X ; T2 = 2 L T1 - X
    k_spmm<<<edgeGrid, B, 0, stream>>>(ind0, ind1, vals, X, T1);
    k_spmm<<<edgeGrid, B, 0, stream>>>(ind0, ind1, vals, T1, T2);
    k_t2_finish<<<2048, B, 0, stream>>>(T2, X);

    // layer 1
    k_gemm1<<<rowGrid, B, 0, stream>>>(X, T1, T2, W1, h);
    k_fill<<<2048, B, 0, stream>>>(acc, 0.0f, (long)N_NODES * 64);
    k_conv<<<edgeGrid, B, 0, stream>>>(ind0, ind1, dis, h, acc);
    k_conv_finish<<<nodeGrid, B, 0, stream>>>(acc, h, dis, b1, x1);

    // layer 2
    k_gemm64<<<rowGrid, B, 0, stream>>>(x1, W2, h);
    k_fill<<<2048, B, 0, stream>>>(acc, 0.0f, (long)N_NODES * 64);
    k_conv<<<edgeGrid, B, 0, stream>>>(ind0, ind1, dis, h, acc);
    k_conv_finish<<<nodeGrid, B, 0, stream>>>(acc, h, dis, b2, x2);

    // layer 3
    k_gemm64<<<rowGrid, B, 0, stream>>>(x2, W3, h);
    k_fill<<<2048, B, 0, stream>>>(acc, 0.0f, (long)N_NODES * 64);
    k_conv<<<edgeGrid, B, 0, stream>>>(ind0, ind1, dis, h, acc);
    k_conv_finish<<<nodeGrid, B, 0, stream>>>(acc, h, dis, b3, x3);

    // pool + head
    k_pool<<<nodeGrid, B, 0, stream>>>(x1, x2, x3, batch, pooled, counts);
    k_out<<<N_GRAPHS, 64, 0, stream>>>(pooled, counts, Wout, bout, out);
}

// Round 2
// 1129.735 us; speedup vs baseline: 1.5422x; 1.5422x over previous
//
#include <hip/hip_runtime.h>
#include <hip/hip_bf16.h>

#define N_NODES 50000
#define N_EDGES 800000
#define IN_DIM 128
#define F_SIZE 64
#define N_GRAPHS 512
#define OUT_DIM 10

// ---------------- CSR build ----------------
__global__ void k_zero_int(int* __restrict__ p, int n) {
    int i = blockIdx.x * blockDim.x + threadIdx.x;
    if (i < n) p[i] = 0;
}

__global__ void k_hist(const int* __restrict__ ind0, const int* __restrict__ ind1,
                       int* __restrict__ deg0, int* __restrict__ deg1) {
    int e = blockIdx.x * blockDim.x + threadIdx.x;
    if (e < N_EDGES) {
        atomicAdd(&deg0[ind0[e]], 1);
        atomicAdd(&deg1[ind1[e]], 1);
    }
}

// single-block exclusive scan over N_NODES counts -> rowptr + cursor copy
__global__ __launch_bounds__(1024) void k_scan(const int* __restrict__ cnt,
                                               int* __restrict__ rp, int* __restrict__ cur) {
    __shared__ int part[1024];
    int t = threadIdx.x;
    const int PER = (N_NODES + 1023) / 1024;   // 49
    int base = t * PER;
    int s = 0;
    for (int k = 0; k < PER; ++k) { int i = base + k; if (i < N_NODES) s += cnt[i]; }
    part[t] = s;
    __syncthreads();
    for (int off = 1; off < 1024; off <<= 1) {
        int v = (t >= off) ? part[t - off] : 0;
        __syncthreads();
        part[t] += v;
        __syncthreads();
    }
    int run = (t == 0) ? 0 : part[t - 1];
    for (int k = 0; k < PER; ++k) {
        int i = base + k;
        if (i < N_NODES) { rp[i] = run; cur[i] = run; run += cnt[i]; }
    }
    if (t == 1023) rp[N_NODES] = part[1023];
}

__global__ void k_dis(const int* __restrict__ deg1, float* __restrict__ dis) {
    int i = blockIdx.x * blockDim.x + threadIdx.x;
    if (i < N_NODES) dis[i] = rsqrtf(1.0f + (float)deg1[i]);  // self-loop included
}

__global__ void k_scatter(const int* __restrict__ ind0, const int* __restrict__ ind1,
                          const float* __restrict__ vals, const float* __restrict__ dis,
                          int* __restrict__ cur0, int* __restrict__ cur1,
                          int* __restrict__ c0col, float* __restrict__ c0val,
                          int* __restrict__ c1src, float* __restrict__ c1norm) {
    int e = blockIdx.x * blockDim.x + threadIdx.x;
    if (e >= N_EDGES) return;
    int r = ind0[e], c = ind1[e];
    int p0 = atomicAdd(&cur0[r], 1);
    c0col[p0] = c; c0val[p0] = vals[e];
    int p1 = atomicAdd(&cur1[c], 1);
    c1src[p1] = r; c1norm[p1] = dis[r] * dis[c];
}

// ---------------- Chebyshev SpMM (gather): dst[i] = sum_j val*src[col] ----------------
// MODE 0: dst = acc        MODE 1: dst = 2*acc - X   (fused T2 finish)
template<int MODE>
__global__ void k_spmm_gather(const int* __restrict__ rp, const int* __restrict__ col,
                              const float* __restrict__ val, const float* __restrict__ src,
                              const float* __restrict__ X, float* __restrict__ dst) {
    int t = blockIdx.x * blockDim.x + threadIdx.x;
    int node = t >> 6, lane = t & 63;
    if (node >= N_NODES) return;
    int s = rp[node], e = rp[node + 1];
    const float2* s2 = (const float2*)src;
    float2 acc = {0.f, 0.f};
    int j = s;
    for (; j + 1 < e; j += 2) {
        float v0 = val[j],     v1 = val[j + 1];
        float2 p0 = s2[(size_t)col[j] * 64 + lane];
        float2 p1 = s2[(size_t)col[j + 1] * 64 + lane];
        acc.x += v0 * p0.x + v1 * p1.x;
        acc.y += v0 * p0.y + v1 * p1.y;
    }
    if (j < e) {
        float v = val[j];
        float2 p = s2[(size_t)col[j] * 64 + lane];
        acc.x += v * p.x; acc.y += v * p.y;
    }
    if (MODE == 1) {
        float2 x = ((const float2*)X)[(size_t)node * 64 + lane];
        acc.x = 2.f * acc.x - x.x;
        acc.y = 2.f * acc.y - x.y;
    }
    ((float2*)dst)[(size_t)node * 64 + lane] = acc;
}

// ---------------- GEMM: h = [X|T1|T2] @ W1  ([N,384]x[384,64]) ----------------
__global__ void k_gemm1(const float* __restrict__ X, const float* __restrict__ T1,
                        const float* __restrict__ T2, const float* __restrict__ W1,
                        float* __restrict__ h) {
    int c  = threadIdx.x & 63;
    int ry = threadIdx.x >> 6;
    int r  = blockIdx.x * 4 + ry;
    if (r >= N_NODES) return;
    const float* xr  = X  + (size_t)r * IN_DIM;
    const float* t1r = T1 + (size_t)r * IN_DIM;
    const float* t2r = T2 + (size_t)r * IN_DIM;
    float acc = 0.f;
    #pragma unroll 4
    for (int k = 0; k < 128; ++k) acc += xr[k]  * W1[(k)       * 64 + c];
    #pragma unroll 4
    for (int k = 0; k < 128; ++k) acc += t1r[k] * W1[(128 + k) * 64 + c];
    #pragma unroll 4
    for (int k = 0; k < 128; ++k) acc += t2r[k] * W1[(256 + k) * 64 + c];
    h[(size_t)r * 64 + c] = acc;
}

// h = x @ W  ([N,64]x[64,64])
__global__ void k_gemm64(const float* __restrict__ x, const float* __restrict__ W,
                         float* __restrict__ h) {
    int c  = threadIdx.x & 63;
    int ry = threadIdx.x >> 6;
    int r  = blockIdx.x * 4 + ry;
    if (r >= N_NODES) return;
    const float* xr = x + (size_t)r * 64;
    float acc = 0.f;
    #pragma unroll 8
    for (int k = 0; k < 64; ++k) acc += xr[k] * W[k * 64 + c];
    h[(size_t)r * 64 + c] = acc;
}

// ---------------- GCN conv (gather) fused with self-loop + bias + relu ----------------
__global__ void k_conv_gather(const int* __restrict__ rp, const int* __restrict__ src,
                              const float* __restrict__ nrm, const float* __restrict__ h,
                              const float* __restrict__ dis, const float* __restrict__ b,
                              float* __restrict__ x) {
    int t = blockIdx.x * blockDim.x + threadIdx.x;
    int node = t >> 6, lane = t & 63;
    if (node >= N_NODES) return;
    int s = rp[node], e = rp[node + 1];
    float a = 0.f;
    int j = s;
    for (; j + 1 < e; j += 2) {
        float n0 = nrm[j], n1 = nrm[j + 1];
        float h0 = h[(size_t)src[j] * 64 + lane];
        float h1 = h[(size_t)src[j + 1] * 64 + lane];
        a += n0 * h0 + n1 * h1;
    }
    if (j < e) a += nrm[j] * h[(size_t)src[j] * 64 + lane];
    float d = dis[node];
    a += d * d * h[(size_t)node * 64 + lane] + b[lane];
    x[(size_t)node * 64 + lane] = fmaxf(a, 0.f);
}

// ---------------- pool (batch is sorted -> contiguous ranges) + head ----------------
__global__ void k_pool_out(const float* __restrict__ x1, const float* __restrict__ x2,
                           const float* __restrict__ x3, const int* __restrict__ batch,
                           const float* __restrict__ Wout, const float* __restrict__ bout,
                           float* __restrict__ out) {
    __shared__ float sh[64];
    __shared__ float logits[OUT_DIM];
    int g = blockIdx.x, f = threadIdx.x;
    int lo = 0, hi = N_NODES;
    while (lo < hi) { int m = (lo + hi) >> 1; if (batch[m] < g) lo = m + 1; else hi = m; }
    int start = lo;
    hi = N_NODES;
    while (lo < hi) { int m = (lo + hi) >> 1; if (batch[m] < g + 1) lo = m + 1; else hi = m; }
    int end = lo;
    float a = 0.f;
    for (int i = start; i < end; ++i)
        a += x1[(size_t)i * 64 + f] + x2[(size_t)i * 64 + f] + x3[(size_t)i * 64 + f];
    float cnt = (float)((end - start) > 0 ? (end - start) : 1);
    sh[f] = a / (3.f * cnt);
    __syncthreads();
    if (f < OUT_DIM) {
        float l = bout[f];
        for (int k = 0; k < 64; ++k) l += sh[k] * Wout[k * OUT_DIM + f];
        logits[f] = l;
    }
    __syncthreads();
    if (f < OUT_DIM) {
        float m = logits[0];
        for (int k = 1; k < OUT_DIM; ++k) m = fmaxf(m, logits[k]);
        float ssum = 0.f;
        for (int k = 0; k < OUT_DIM; ++k) ssum += expf(logits[k] - m);
        out[(size_t)g * OUT_DIM + f] = expf(logits[f] - m) / ssum;
    }
}

extern "C" void kernel_launch(void* const* d_in, const int* in_sizes, int n_in,
                              void* d_out, int out_size, void* d_ws, size_t ws_size,
                              hipStream_t stream) {
    const float* X     = (const float*)d_in[0];
    const int*   Lind  = (const int*)d_in[1];
    const int*   ind0  = Lind;
    const int*   ind1  = Lind + N_EDGES;
    const float* vals  = (const float*)d_in[2];
    const int*   batch = (const int*)d_in[3];
    const float* W1    = (const float*)d_in[4];
    const float* b1    = (const float*)d_in[5];
    const float* W2    = (const float*)d_in[6];
    const float* b2    = (const float*)d_in[7];
    const float* W3    = (const float*)d_in[8];
    const float* b3    = (const float*)d_in[9];
    const float* Wout  = (const float*)d_in[10];
    const float* bout  = (const float*)d_in[11];
    float* out = (float*)d_out;

    // workspace layout (4B words; rp padded to keep 8B alignment downstream)
    int* deg0   = (int*)d_ws;              // 50000
    int* deg1   = deg0 + 50000;            // 50000
    int* rp0    = deg1 + 50000;            // 50002 (padded)
    int* rp1    = rp0  + 50002;            // 50002 (padded)
    int* cur0   = rp1  + 50002;            // 50000
    int* cur1   = cur0 + 50000;            // 50000
    int* c0col  = cur1 + 50000;            // 800000
    int* c1src  = c0col + 800000;          // 800000
    float* c0val  = (float*)(c1src + 800000);  // 800000
    float* c1norm = c0val + 800000;        // 800000
    float* dis    = c1norm + 800000;       // 50000
    float* T1     = dis + 50000;           // 6,400,000 (even word offset -> 8B aligned)
    float* T2     = T1 + 6400000;
    float* h      = T2 + 6400000;          // 3,200,000
    float* x1     = h  + 3200000;
    float* x2     = x1 + 3200000;
    float* x3     = x2 + 3200000;

    const int B = 256;
    const int edgeGrid = (N_EDGES + B - 1) / B;       // 3125
    const int nodeWaveGrid = (N_NODES * 64) / B;      // 12500
    const int rowGrid  = (N_NODES + 3) / 4;

    // CSR build
    k_zero_int<<<(100000 + B - 1) / B, B, 0, stream>>>(deg0, 100000);  // deg0+deg1 contiguous
    k_hist<<<edgeGrid, B, 0, stream>>>(ind0, ind1, deg0, deg1);
    k_scan<<<1, 1024, 0, stream>>>(deg0, rp0, cur0);
    k_scan<<<1, 1024, 0, stream>>>(deg1, rp1, cur1);
    k_dis<<<(N_NODES + B - 1) / B, B, 0, stream>>>(deg1, dis);
    k_scatter<<<edgeGrid, B, 0, stream>>>(ind0, ind1, vals, dis, cur0, cur1,
                                          c0col, c0val, c1src, c1norm);

    // Chebyshev: T1 = L X ; T2 = 2 L T1 - X (fused)
    k_spmm_gather<0><<<nodeWaveGrid, B, 0, stream>>>(rp0, c0col, c0val, X,  nullptr, T1);
    k_spmm_gather<1><<<nodeWaveGrid, B, 0, stream>>>(rp0, c0col, c0val, T1, X,       T2);

    // layer 1
    k_gemm1<<<rowGrid, B, 0, stream>>>(X, T1, T2, W1, h);
    k_conv_gather<<<nodeWaveGrid, B, 0, stream>>>(rp1, c1src, c1norm, h, dis, b1, x1);

    // layer 2
    k_gemm64<<<rowGrid, B, 0, stream>>>(x1, W2, h);
    k_conv_gather<<<nodeWaveGrid, B, 0, stream>>>(rp1, c1src, c1norm, h, dis, b2, x2);

    // layer 3
    k_gemm64<<<rowGrid, B, 0, stream>>>(x2, W3, h);
    k_conv_gather<<<nodeWaveGrid, B, 0, stream>>>(rp1, c1src, c1norm, h, dis, b3, x3);

    // pool + head
    k_pool_out<<<N_GRAPHS, 64, 0, stream>>>(x1, x2, x3, batch, Wout, bout, out);
}

// Round 3
// 961.279 us; speedup vs baseline: 1.8125x; 1.1752x over previous
//
#include <hip/hip_runtime.h>
#include <hip/hip_bf16.h>

#define N_NODES 50000
#define N_EDGES 800000
#define IN_DIM 128
#define F_SIZE 64
#define N_GRAPHS 512
#define OUT_DIM 10

// ---------------- CSR build ----------------
__global__ void k_zero_int(int* __restrict__ p, int n) {
    int i = blockIdx.x * blockDim.x + threadIdx.x;
    if (i < n) p[i] = 0;
}

__global__ void k_hist(const int* __restrict__ ind0, const int* __restrict__ ind1,
                       int* __restrict__ deg0, int* __restrict__ deg1) {
    int e = blockIdx.x * blockDim.x + threadIdx.x;
    if (e < N_EDGES) {
        atomicAdd(&deg0[ind0[e]], 1);
        atomicAdd(&deg1[ind1[e]], 1);
    }
}

// single-block exclusive scan over N_NODES counts -> rowptr + cursor copy
__global__ __launch_bounds__(1024) void k_scan(const int* __restrict__ cnt,
                                               int* __restrict__ rp, int* __restrict__ cur) {
    __shared__ int part[1024];
    int t = threadIdx.x;
    const int PER = (N_NODES + 1023) / 1024;   // 49
    int base = t * PER;
    int s = 0;
    for (int k = 0; k < PER; ++k) { int i = base + k; if (i < N_NODES) s += cnt[i]; }
    part[t] = s;
    __syncthreads();
    for (int off = 1; off < 1024; off <<= 1) {
        int v = (t >= off) ? part[t - off] : 0;
        __syncthreads();
        part[t] += v;
        __syncthreads();
    }
    int run = (t == 0) ? 0 : part[t - 1];
    for (int k = 0; k < PER; ++k) {
        int i = base + k;
        if (i < N_NODES) { rp[i] = run; cur[i] = run; run += cnt[i]; }
    }
    if (t == 1023) rp[N_NODES] = part[1023];
}

__global__ void k_dis(const int* __restrict__ deg1, float* __restrict__ dis) {
    int i = blockIdx.x * blockDim.x + threadIdx.x;
    if (i < N_NODES) dis[i] = rsqrtf(1.0f + (float)deg1[i]);  // self-loop included
}

__global__ void k_scatter(const int* __restrict__ ind0, const int* __restrict__ ind1,
                          const float* __restrict__ vals, const float* __restrict__ dis,
                          int* __restrict__ cur0, int* __restrict__ cur1,
                          int* __restrict__ c0col, float* __restrict__ c0val,
                          int* __restrict__ c1src, float* __restrict__ c1norm) {
    int e = blockIdx.x * blockDim.x + threadIdx.x;
    if (e >= N_EDGES) return;
    int r = ind0[e], c = ind1[e];
    int p0 = atomicAdd(&cur0[r], 1);
    c0col[p0] = c; c0val[p0] = vals[e];
    int p1 = atomicAdd(&cur1[c], 1);
    c1src[p1] = r; c1norm[p1] = dis[r] * dis[c];
}

// ---------------- Chebyshev SpMM (gather): dst[i] = sum_j val*src[col] ----------------
// MODE 0: dst = acc        MODE 1: dst = 2*acc - X   (fused T2 finish)
template<int MODE>
__global__ void k_spmm_gather(const int* __restrict__ rp, const int* __restrict__ col,
                              const float* __restrict__ val, const float* __restrict__ src,
                              const float* __restrict__ X, float* __restrict__ dst) {
    int t = blockIdx.x * blockDim.x + threadIdx.x;
    int node = t >> 6, lane = t & 63;
    if (node >= N_NODES) return;
    int s = rp[node], e = rp[node + 1];
    const float2* s2 = (const float2*)src;
    float2 acc = {0.f, 0.f};
    int j = s;
    for (; j + 3 < e; j += 4) {
        float v0 = val[j], v1 = val[j + 1], v2 = val[j + 2], v3 = val[j + 3];
        float2 p0 = s2[(size_t)col[j]     * 64 + lane];
        float2 p1 = s2[(size_t)col[j + 1] * 64 + lane];
        float2 p2 = s2[(size_t)col[j + 2] * 64 + lane];
        float2 p3 = s2[(size_t)col[j + 3] * 64 + lane];
        acc.x += v0 * p0.x + v1 * p1.x + v2 * p2.x + v3 * p3.x;
        acc.y += v0 * p0.y + v1 * p1.y + v2 * p2.y + v3 * p3.y;
    }
    for (; j < e; ++j) {
        float v = val[j];
        float2 p = s2[(size_t)col[j] * 64 + lane];
        acc.x += v * p.x; acc.y += v * p.y;
    }
    if (MODE == 1) {
        float2 x = ((const float2*)X)[(size_t)node * 64 + lane];
        acc.x = 2.f * acc.x - x.x;
        acc.y = 2.f * acc.y - x.y;
    }
    ((float2*)dst)[(size_t)node * 64 + lane] = acc;
}

// ---------------- GEMM1: h = [X|T1|T2] @ W1 ([N,384]x[384,64]) ----------------
// wave = 8 rows x 64 cols; W column loads amortized over 8 rows; row elements
// are wave-uniform float4 loads (scalar-cache path).
__global__ __launch_bounds__(256) void k_gemm1(const float* __restrict__ X, const float* __restrict__ T1,
                        const float* __restrict__ T2, const float* __restrict__ W1,
                        float* __restrict__ h) {
    int lane = threadIdx.x & 63;
    int wv   = threadIdx.x >> 6;
    int r0 = (blockIdx.x * 4 + wv) * 8;
    if (r0 + 8 > N_NODES) return;          // N_NODES % 8 == 0: full waves only
    float acc[8] = {0.f,0.f,0.f,0.f,0.f,0.f,0.f,0.f};
    const float* segs[3] = {X, T1, T2};
    for (int sg = 0; sg < 3; ++sg) {
        const float* src = segs[sg] + (size_t)r0 * IN_DIM;
        const float* Wp  = W1 + (size_t)sg * IN_DIM * 64 + lane;
        for (int k = 0; k < IN_DIM; k += 4) {
            float w0 = Wp[(k + 0) * 64], w1 = Wp[(k + 1) * 64];
            float w2 = Wp[(k + 2) * 64], w3 = Wp[(k + 3) * 64];
            #pragma unroll
            for (int r = 0; r < 8; ++r) {
                float4 xv = *(const float4*)(src + r * IN_DIM + k);
                acc[r] += xv.x * w0 + xv.y * w1 + xv.z * w2 + xv.w * w3;
            }
        }
    }
    #pragma unroll
    for (int r = 0; r < 8; ++r)
        h[(size_t)(r0 + r) * 64 + lane] = acc[r];
}

// h = x @ W ([N,64]x[64,64]) — same 8-row register blocking
__global__ __launch_bounds__(256) void k_gemm64(const float* __restrict__ x, const float* __restrict__ W,
                         float* __restrict__ h) {
    int lane = threadIdx.x & 63;
    int wv   = threadIdx.x >> 6;
    int r0 = (blockIdx.x * 4 + wv) * 8;
    if (r0 + 8 > N_NODES) return;
    float acc[8] = {0.f,0.f,0.f,0.f,0.f,0.f,0.f,0.f};
    const float* src = x + (size_t)r0 * 64;
    for (int k = 0; k < 64; k += 4) {
        float w0 = W[(k + 0) * 64 + lane], w1 = W[(k + 1) * 64 + lane];
        float w2 = W[(k + 2) * 64 + lane], w3 = W[(k + 3) * 64 + lane];
        #pragma unroll
        for (int r = 0; r < 8; ++r) {
            float4 xv = *(const float4*)(src + r * 64 + k);
            acc[r] += xv.x * w0 + xv.y * w1 + xv.z * w2 + xv.w * w3;
        }
    }
    #pragma unroll
    for (int r = 0; r < 8; ++r)
        h[(size_t)(r0 + r) * 64 + lane] = acc[r];
}

// ---------------- GCN conv (gather) fused with self-loop + bias + relu ----------------
__global__ void k_conv_gather(const int* __restrict__ rp, const int* __restrict__ src,
                              const float* __restrict__ nrm, const float* __restrict__ h,
                              const float* __restrict__ dis, const float* __restrict__ b,
                              float* __restrict__ x) {
    int t = blockIdx.x * blockDim.x + threadIdx.x;
    int node = t >> 6, lane = t & 63;
    if (node >= N_NODES) return;
    int s = rp[node], e = rp[node + 1];
    float a = 0.f;
    int j = s;
    for (; j + 3 < e; j += 4) {
        float n0 = nrm[j], n1 = nrm[j + 1], n2 = nrm[j + 2], n3 = nrm[j + 3];
        float h0 = h[(size_t)src[j]     * 64 + lane];
        float h1 = h[(size_t)src[j + 1] * 64 + lane];
        float h2 = h[(size_t)src[j + 2] * 64 + lane];
        float h3 = h[(size_t)src[j + 3] * 64 + lane];
        a += n0 * h0 + n1 * h1 + n2 * h2 + n3 * h3;
    }
    for (; j < e; ++j) a += nrm[j] * h[(size_t)src[j] * 64 + lane];
    float d = dis[node];
    a += d * d * h[(size_t)node * 64 + lane] + b[lane];
    x[(size_t)node * 64 + lane] = fmaxf(a, 0.f);
}

// ---------------- pool (batch is sorted -> contiguous ranges) + head ----------------
__global__ void k_pool_out(const float* __restrict__ x1, const float* __restrict__ x2,
                           const float* __restrict__ x3, const int* __restrict__ batch,
                           const float* __restrict__ Wout, const float* __restrict__ bout,
                           float* __restrict__ out) {
    __shared__ float sh[64];
    __shared__ float logits[OUT_DIM];
    int g = blockIdx.x, f = threadIdx.x;
    int lo = 0, hi = N_NODES;
    while (lo < hi) { int m = (lo + hi) >> 1; if (batch[m] < g) lo = m + 1; else hi = m; }
    int start = lo;
    hi = N_NODES;
    while (lo < hi) { int m = (lo + hi) >> 1; if (batch[m] < g + 1) lo = m + 1; else hi = m; }
    int end = lo;
    float a = 0.f;
    for (int i = start; i < end; ++i)
        a += x1[(size_t)i * 64 + f] + x2[(size_t)i * 64 + f] + x3[(size_t)i * 64 + f];
    float cnt = (float)((end - start) > 0 ? (end - start) : 1);
    sh[f] = a / (3.f * cnt);
    __syncthreads();
    if (f < OUT_DIM) {
        float l = bout[f];
        for (int k = 0; k < 64; ++k) l += sh[k] * Wout[k * OUT_DIM + f];
        logits[f] = l;
    }
    __syncthreads();
    if (f < OUT_DIM) {
        float m = logits[0];
        for (int k = 1; k < OUT_DIM; ++k) m = fmaxf(m, logits[k]);
        float ssum = 0.f;
        for (int k = 0; k < OUT_DIM; ++k) ssum += expf(logits[k] - m);
        out[(size_t)g * OUT_DIM + f] = expf(logits[f] - m) / ssum;
    }
}

extern "C" void kernel_launch(void* const* d_in, const int* in_sizes, int n_in,
                              void* d_out, int out_size, void* d_ws, size_t ws_size,
                              hipStream_t stream) {
    const float* X     = (const float*)d_in[0];
    const int*   Lind  = (const int*)d_in[1];
    const int*   ind0  = Lind;
    const int*   ind1  = Lind + N_EDGES;
    const float* vals  = (const float*)d_in[2];
    const int*   batch = (const int*)d_in[3];
    const float* W1    = (const float*)d_in[4];
    const float* b1    = (const float*)d_in[5];
    const float* W2    = (const float*)d_in[6];
    const float* b2    = (const float*)d_in[7];
    const float* W3    = (const float*)d_in[8];
    const float* b3    = (const float*)d_in[9];
    const float* Wout  = (const float*)d_in[10];
    const float* bout  = (const float*)d_in[11];
    float* out = (float*)d_out;

    // workspace layout (4B words; rp padded to keep 8B/16B alignment downstream)
    int* deg0   = (int*)d_ws;              // 50000
    int* deg1   = deg0 + 50000;            // 50000
    int* rp0    = deg1 + 50000;            // 50002 (padded)
    int* rp1    = rp0  + 50002;            // 50002 (padded)
    int* cur0   = rp1  + 50002;            // 50000
    int* cur1   = cur0 + 50000;            // 50000
    int* c0col  = cur1 + 50000;            // 800000
    int* c1src  = c0col + 800000;          // 800000
    float* c0val  = (float*)(c1src + 800000);  // 800000
    float* c1norm = c0val + 800000;        // 800000
    float* dis    = c1norm + 800000;       // 50000
    float* T1     = dis + 50000;           // 6,400,000 (16B-aligned offset)
    float* T2     = T1 + 6400000;
    float* h      = T2 + 6400000;          // 3,200,000
    float* x1     = h  + 3200000;
    float* x2     = x1 + 3200000;
    float* x3     = x2 + 3200000;

    const int B = 256;
    const int edgeGrid = (N_EDGES + B - 1) / B;       // 3125
    const int nodeWaveGrid = (N_NODES * 64) / B;      // 12500
    const int rowGrid8 = (N_NODES / 8 + 3) / 4;       // 1563 blocks, 8 rows/wave

    // CSR build
    k_zero_int<<<(100000 + B - 1) / B, B, 0, stream>>>(deg0, 100000);  // deg0+deg1 contiguous
    k_hist<<<edgeGrid, B, 0, stream>>>(ind0, ind1, deg0, deg1);
    k_scan<<<1, 1024, 0, stream>>>(deg0, rp0, cur0);
    k_scan<<<1, 1024, 0, stream>>>(deg1, rp1, cur1);
    k_dis<<<(N_NODES + B - 1) / B, B, 0, stream>>>(deg1, dis);
    k_scatter<<<edgeGrid, B, 0, stream>>>(ind0, ind1, vals, dis, cur0, cur1,
                                          c0col, c0val, c1src, c1norm);

    // Chebyshev: T1 = L X ; T2 = 2 L T1 - X (fused)
    k_spmm_gather<0><<<nodeWaveGrid, B, 0, stream>>>(rp0, c0col, c0val, X,  nullptr, T1);
    k_spmm_gather<1><<<nodeWaveGrid, B, 0, stream>>>(rp0, c0col, c0val, T1, X,       T2);

    // layer 1
    k_gemm1<<<rowGrid8, B, 0, stream>>>(X, T1, T2, W1, h);
    k_conv_gather<<<nodeWaveGrid, B, 0, stream>>>(rp1, c1src, c1norm, h, dis, b1, x1);

    // layer 2
    k_gemm64<<<rowGrid8, B, 0, stream>>>(x1, W2, h);
    k_conv_gather<<<nodeWaveGrid, B, 0, stream>>>(rp1, c1src, c1norm, h, dis, b2, x2);

    // layer 3
    k_gemm64<<<rowGrid8, B, 0, stream>>>(x2, W3, h);
    k_conv_gather<<<nodeWaveGrid, B, 0, stream>>>(rp1, c1src, c1norm, h, dis, b3, x3);

    // pool + head
    k_pool_out<<<N_GRAPHS, 64, 0, stream>>>(x1, x2, x3, batch, Wout, bout, out);
}

// Round 4
// 774.163 us; speedup vs baseline: 2.2506x; 1.2417x over previous
//
#include <hip/hip_runtime.h>
#include <hip/hip_bf16.h>

#define N_NODES 50000
#define N_EDGES 800000
#define IN_DIM 128
#define F_SIZE 64
#define N_GRAPHS 512
#define OUT_DIM 10

// ---------------- CSR build ----------------
__global__ void k_zero_int(int* __restrict__ p, int n) {
    int i = blockIdx.x * blockDim.x + threadIdx.x;
    if (i < n) p[i] = 0;
}

__global__ void k_hist(const int* __restrict__ ind0, const int* __restrict__ ind1,
                       int* __restrict__ deg0, int* __restrict__ deg1) {
    int e = blockIdx.x * blockDim.x + threadIdx.x;
    if (e < N_EDGES) {
        atomicAdd(&deg0[ind0[e]], 1);
        atomicAdd(&deg1[ind1[e]], 1);
    }
}

// single-block exclusive scan over N_NODES counts -> rowptr + cursor copy
__global__ __launch_bounds__(1024) void k_scan(const int* __restrict__ cnt,
                                               int* __restrict__ rp, int* __restrict__ cur) {
    __shared__ int part[1024];
    int t = threadIdx.x;
    const int PER = (N_NODES + 1023) / 1024;   // 49
    int base = t * PER;
    int s = 0;
    for (int k = 0; k < PER; ++k) { int i = base + k; if (i < N_NODES) s += cnt[i]; }
    part[t] = s;
    __syncthreads();
    for (int off = 1; off < 1024; off <<= 1) {
        int v = (t >= off) ? part[t - off] : 0;
        __syncthreads();
        part[t] += v;
        __syncthreads();
    }
    int run = (t == 0) ? 0 : part[t - 1];
    for (int k = 0; k < PER; ++k) {
        int i = base + k;
        if (i < N_NODES) { rp[i] = run; cur[i] = run; run += cnt[i]; }
    }
    if (t == 1023) rp[N_NODES] = part[1023];
}

__global__ void k_dis(const int* __restrict__ deg1, float* __restrict__ dis) {
    int i = blockIdx.x * blockDim.x + threadIdx.x;
    if (i < N_NODES) dis[i] = rsqrtf(1.0f + (float)deg1[i]);  // self-loop included
}

__global__ void k_scatter(const int* __restrict__ ind0, const int* __restrict__ ind1,
                          const float* __restrict__ vals, const float* __restrict__ dis,
                          int* __restrict__ cur0, int* __restrict__ cur1,
                          int* __restrict__ c0col, float* __restrict__ c0val,
                          int* __restrict__ c1src, float* __restrict__ c1norm) {
    int e = blockIdx.x * blockDim.x + threadIdx.x;
    if (e >= N_EDGES) return;
    int r = ind0[e], c = ind1[e];
    int p0 = atomicAdd(&cur0[r], 1);
    c0col[p0] = c; c0val[p0] = vals[e];
    int p1 = atomicAdd(&cur1[c], 1);
    c1src[p1] = r; c1norm[p1] = dis[r] * dis[c];
}

// ---------------- Chebyshev SpMM (gather): dst[i] = sum_j val*src[col] ----------------
// MODE 0: dst = acc        MODE 1: dst = 2*acc - X   (fused T2 finish)
template<int MODE>
__global__ void k_spmm_gather(const int* __restrict__ rp, const int* __restrict__ col,
                              const float* __restrict__ val, const float* __restrict__ src,
                              const float* __restrict__ X, float* __restrict__ dst) {
    int t = blockIdx.x * blockDim.x + threadIdx.x;
    int node = t >> 6, lane = t & 63;
    if (node >= N_NODES) return;
    int s = rp[node], e = rp[node + 1];
    const float2* s2 = (const float2*)src;
    float2 acc = {0.f, 0.f};
    int j = s;
    for (; j + 3 < e; j += 4) {
        float v0 = val[j], v1 = val[j + 1], v2 = val[j + 2], v3 = val[j + 3];
        float2 p0 = s2[(size_t)col[j]     * 64 + lane];
        float2 p1 = s2[(size_t)col[j + 1] * 64 + lane];
        float2 p2 = s2[(size_t)col[j + 2] * 64 + lane];
        float2 p3 = s2[(size_t)col[j + 3] * 64 + lane];
        acc.x += v0 * p0.x + v1 * p1.x + v2 * p2.x + v3 * p3.x;
        acc.y += v0 * p0.y + v1 * p1.y + v2 * p2.y + v3 * p3.y;
    }
    for (; j < e; ++j) {
        float v = val[j];
        float2 p = s2[(size_t)col[j] * 64 + lane];
        acc.x += v * p.x; acc.y += v * p.y;
    }
    if (MODE == 1) {
        float2 x = ((const float2*)X)[(size_t)node * 64 + lane];
        acc.x = 2.f * acc.x - x.x;
        acc.y = 2.f * acc.y - x.y;
    }
    ((float2*)dst)[(size_t)node * 64 + lane] = acc;
}

// ---------------- LDS-tiled fp32 GEMM: C[M,64] = [s0|s1|s2] @ W ----------------
// RS = per-segment row stride (K per segment), NSEG segments concat along K.
// Block 256 thr -> 64x64 tile, BK=64, thread = 4x4 micro-tile.
#define AT_STRIDE 68
template<int RS, int NSEG>
__global__ __launch_bounds__(256) void k_gemm_lds(const float* __restrict__ s0,
                                                  const float* __restrict__ s1,
                                                  const float* __restrict__ s2,
                                                  const float* __restrict__ W,
                                                  float* __restrict__ C) {
    constexpr int CHUNKS = NSEG * RS / 64;
    __shared__ float At[64 * AT_STRIDE];   // A transposed: At[k][row], padded stride
    __shared__ float Wl[64 * 64];          // W chunk as-is: Wl[k][col]
    const int t = threadIdx.x;
    const int l = t & 63, w = t >> 6;
    const int r0 = blockIdx.x * 64;
    const int rbase = w * 16 + (l >> 4) * 4;   // this thread's 4 rows (tile-local)
    const int cbase = (l & 15) * 4;            // this thread's 4 cols
    float acc[4][4] = {};

    #pragma unroll
    for (int ch = 0; ch < CHUNKS; ++ch) {
        const float* A = (NSEG == 1) ? s0 : (ch < RS / 64 ? s0 : (ch < 2 * (RS / 64) ? s1 : s2));
        const int koff = (NSEG == 1) ? (ch * 64) : ((ch % (RS / 64)) * 64);
        // stage W chunk (contiguous 16 KB), flat coalesced copy
        {
            const float4* Wg = (const float4*)(W + (size_t)ch * 4096);
            #pragma unroll
            for (int i = 0; i < 4; ++i) {
                *(float4*)&Wl[(i * 256 + t) * 4] = Wg[i * 256 + t];
            }
        }
        // stage A chunk, transposed into At[k][row]
        #pragma unroll
        for (int i = 0; i < 4; ++i) {
            int f   = i * 256 + t;      // float4 id within 64x64 tile
            int row = f >> 4;           // 0..63
            int kq  = f & 15;           // float4 within row
            int gr  = r0 + row; if (gr > N_NODES - 1) gr = N_NODES - 1;
            float4 v = *(const float4*)(A + (size_t)gr * RS + koff + kq * 4);
            At[(kq * 4 + 0) * AT_STRIDE + row] = v.x;
            At[(kq * 4 + 1) * AT_STRIDE + row] = v.y;
            At[(kq * 4 + 2) * AT_STRIDE + row] = v.z;
            At[(kq * 4 + 3) * AT_STRIDE + row] = v.w;
        }
        __syncthreads();
        #pragma unroll 8
        for (int k = 0; k < 64; ++k) {
            float4 a4 = *(const float4*)&At[k * AT_STRIDE + rbase];
            float4 w4 = *(const float4*)&Wl[k * 64 + cbase];
            acc[0][0] += a4.x * w4.x; acc[0][1] += a4.x * w4.y; acc[0][2] += a4.x * w4.z; acc[0][3] += a4.x * w4.w;
            acc[1][0] += a4.y * w4.x; acc[1][1] += a4.y * w4.y; acc[1][2] += a4.y * w4.z; acc[1][3] += a4.y * w4.w;
            acc[2][0] += a4.z * w4.x; acc[2][1] += a4.z * w4.y; acc[2][2] += a4.z * w4.z; acc[2][3] += a4.z * w4.w;
            acc[3][0] += a4.w * w4.x; acc[3][1] += a4.w * w4.y; acc[3][2] += a4.w * w4.z; acc[3][3] += a4.w * w4.w;
        }
        __syncthreads();
    }
    #pragma unroll
    for (int r = 0; r < 4; ++r) {
        int gr = r0 + rbase + r;
        if (gr < N_NODES) {
            float4 o = {acc[r][0], acc[r][1], acc[r][2], acc[r][3]};
            *(float4*)&C[(size_t)gr * 64 + cbase] = o;
        }
    }
}

// ---------------- GCN conv (gather) fused with self-loop + bias + relu ----------------
__global__ void k_conv_gather(const int* __restrict__ rp, const int* __restrict__ src,
                              const float* __restrict__ nrm, const float* __restrict__ h,
                              const float* __restrict__ dis, const float* __restrict__ b,
                              float* __restrict__ x) {
    int t = blockIdx.x * blockDim.x + threadIdx.x;
    int node = t >> 6, lane = t & 63;
    if (node >= N_NODES) return;
    int s = rp[node], e = rp[node + 1];
    float a = 0.f;
    int j = s;
    for (; j + 3 < e; j += 4) {
        float n0 = nrm[j], n1 = nrm[j + 1], n2 = nrm[j + 2], n3 = nrm[j + 3];
        float h0 = h[(size_t)src[j]     * 64 + lane];
        float h1 = h[(size_t)src[j + 1] * 64 + lane];
        float h2 = h[(size_t)src[j + 2] * 64 + lane];
        float h3 = h[(size_t)src[j + 3] * 64 + lane];
        a += n0 * h0 + n1 * h1 + n2 * h2 + n3 * h3;
    }
    for (; j < e; ++j) a += nrm[j] * h[(size_t)src[j] * 64 + lane];
    float d = dis[node];
    a += d * d * h[(size_t)node * 64 + lane] + b[lane];
    x[(size_t)node * 64 + lane] = fmaxf(a, 0.f);
}

// ---------------- pool (batch sorted -> contiguous ranges) + head, 4 waves ----------------
__global__ __launch_bounds__(256) void k_pool_out(const float* __restrict__ x1,
                           const float* __restrict__ x2,
                           const float* __restrict__ x3, const int* __restrict__ batch,
                           const float* __restrict__ Wout, const float* __restrict__ bout,
                           float* __restrict__ out) {
    __shared__ float red[4][64];
    __shared__ float sh[64];
    __shared__ float logits[OUT_DIM];
    int g = blockIdx.x;
    int t = threadIdx.x, f = t & 63, w = t >> 6;
    int lo = 0, hi = N_NODES;
    while (lo < hi) { int m = (lo + hi) >> 1; if (batch[m] < g) lo = m + 1; else hi = m; }
    int start = lo;
    hi = N_NODES;
    while (lo < hi) { int m = (lo + hi) >> 1; if (batch[m] < g + 1) lo = m + 1; else hi = m; }
    int end = lo;
    float a = 0.f;
    for (int i = start + w; i < end; i += 4)
        a += x1[(size_t)i * 64 + f] + x2[(size_t)i * 64 + f] + x3[(size_t)i * 64 + f];
    red[w][f] = a;
    __syncthreads();
    if (w == 0) {
        float cnt = (float)((end - start) > 0 ? (end - start) : 1);
        sh[f] = (red[0][f] + red[1][f] + red[2][f] + red[3][f]) / (3.f * cnt);
    }
    __syncthreads();
    if (t < OUT_DIM) {
        float l = bout[t];
        for (int k = 0; k < 64; ++k) l += sh[k] * Wout[k * OUT_DIM + t];
        logits[t] = l;
    }
    __syncthreads();
    if (t < OUT_DIM) {
        float m = logits[0];
        for (int k = 1; k < OUT_DIM; ++k) m = fmaxf(m, logits[k]);
        float ssum = 0.f;
        for (int k = 0; k < OUT_DIM; ++k) ssum += expf(logits[k] - m);
        out[(size_t)g * OUT_DIM + t] = expf(logits[t] - m) / ssum;
    }
}

extern "C" void kernel_launch(void* const* d_in, const int* in_sizes, int n_in,
                              void* d_out, int out_size, void* d_ws, size_t ws_size,
                              hipStream_t stream) {
    const float* X     = (const float*)d_in[0];
    const int*   Lind  = (const int*)d_in[1];
    const int*   ind0  = Lind;
    const int*   ind1  = Lind + N_EDGES;
    const float* vals  = (const float*)d_in[2];
    const int*   batch = (const int*)d_in[3];
    const float* W1    = (const float*)d_in[4];
    const float* b1    = (const float*)d_in[5];
    const float* W2    = (const float*)d_in[6];
    const float* b2    = (const float*)d_in[7];
    const float* W3    = (const float*)d_in[8];
    const float* b3    = (const float*)d_in[9];
    const float* Wout  = (const float*)d_in[10];
    const float* bout  = (const float*)d_in[11];
    float* out = (float*)d_out;

    // workspace layout (4B words; offsets keep 16B alignment for float4 paths)
    int* deg0   = (int*)d_ws;              // 50000
    int* deg1   = deg0 + 50000;            // 50000
    int* rp0    = deg1 + 50000;            // 50002 (padded)
    int* rp1    = rp0  + 50002;            // 50002 (padded)
    int* cur0   = rp1  + 50002;            // 50000
    int* cur1   = cur0 + 50000;            // 50000
    int* c0col  = cur1 + 50000;            // 800000
    int* c1src  = c0col + 800000;          // 800000
    float* c0val  = (float*)(c1src + 800000);  // 800000
    float* c1norm = c0val + 800000;        // 800000
    float* dis    = c1norm + 800000;       // 50000
    float* T1     = dis + 50000;           // 6,400,000 (word offset %4==0 -> 16B aligned)
    float* T2     = T1 + 6400000;
    float* h      = T2 + 6400000;          // 3,200,000
    float* x1     = h  + 3200000;
    float* x2     = x1 + 3200000;
    float* x3     = x2 + 3200000;

    const int B = 256;
    const int edgeGrid = (N_EDGES + B - 1) / B;       // 3125
    const int nodeWaveGrid = (N_NODES * 64) / B;      // 12500
    const int tileGrid = (N_NODES + 63) / 64;         // 782

    // CSR build
    k_zero_int<<<(100000 + B - 1) / B, B, 0, stream>>>(deg0, 100000);  // deg0+deg1 contiguous
    k_hist<<<edgeGrid, B, 0, stream>>>(ind0, ind1, deg0, deg1);
    k_scan<<<1, 1024, 0, stream>>>(deg0, rp0, cur0);
    k_scan<<<1, 1024, 0, stream>>>(deg1, rp1, cur1);
    k_dis<<<(N_NODES + B - 1) / B, B, 0, stream>>>(deg1, dis);
    k_scatter<<<edgeGrid, B, 0, stream>>>(ind0, ind1, vals, dis, cur0, cur1,
                                          c0col, c0val, c1src, c1norm);

    // Chebyshev: T1 = L X ; T2 = 2 L T1 - X (fused)
    k_spmm_gather<0><<<nodeWaveGrid, B, 0, stream>>>(rp0, c0col, c0val, X,  nullptr, T1);
    k_spmm_gather<1><<<nodeWaveGrid, B, 0, stream>>>(rp0, c0col, c0val, T1, X,       T2);

    // layer 1
    k_gemm_lds<128, 3><<<tileGrid, B, 0, stream>>>(X, T1, T2, W1, h);
    k_conv_gather<<<nodeWaveGrid, B, 0, stream>>>(rp1, c1src, c1norm, h, dis, b1, x1);

    // layer 2
    k_gemm_lds<64, 1><<<tileGrid, B, 0, stream>>>(x1, x1, x1, W2, h);
    k_conv_gather<<<nodeWaveGrid, B, 0, stream>>>(rp1, c1src, c1norm, h, dis, b2, x2);

    // layer 3
    k_gemm_lds<64, 1><<<tileGrid, B, 0, stream>>>(x2, x2, x2, W3, h);
    k_conv_gather<<<nodeWaveGrid, B, 0, stream>>>(rp1, c1src, c1norm, h, dis, b3, x3);

    // pool + head
    k_pool_out<<<N_GRAPHS, B, 0, stream>>>(x1, x2, x3, batch, Wout, bout, out);
}

// Round 5
// 538.554 us; speedup vs baseline: 3.2352x; 1.4375x over previous
//
#include <hip/hip_runtime.h>
#include <hip/hip_bf16.h>

#define N_NODES 50000
#define N_EDGES 800000
#define IN_DIM 128
#define F_SIZE 64
#define N_GRAPHS 512
#define OUT_DIM 10
#define SCAN_BLOCKS 196   // ceil(50000/256)

// ---------------- CSR build ----------------
__global__ void k_zero_int(int* __restrict__ p, int n) {
    int i = blockIdx.x * blockDim.x + threadIdx.x;
    if (i < n) p[i] = 0;
}

__global__ void k_hist(const int* __restrict__ ind0, const int* __restrict__ ind1,
                       int* __restrict__ deg0, int* __restrict__ deg1) {
    int e = blockIdx.x * blockDim.x + threadIdx.x;
    if (e < N_EDGES) {
        atomicAdd(&deg0[ind0[e]], 1);
        atomicAdd(&deg1[ind1[e]], 1);
    }
}

// ---- hierarchical exclusive scan over deg0 (blocks 0..195) and deg1 (196..391) ----
__global__ __launch_bounds__(256) void k_scan_red(const int* __restrict__ cnt0,
                                                  const int* __restrict__ cnt1,
                                                  int* __restrict__ blksum) {
    int blk = blockIdx.x;
    const int* cnt = (blk < SCAN_BLOCKS) ? cnt0 : cnt1;
    int lb = (blk < SCAN_BLOCKS) ? blk : blk - SCAN_BLOCKS;
    int i = lb * 256 + threadIdx.x;
    int v = (i < N_NODES) ? cnt[i] : 0;
    #pragma unroll
    for (int off = 32; off; off >>= 1) v += __shfl_down(v, off, 64);
    __shared__ int ws[4];
    if ((threadIdx.x & 63) == 0) ws[threadIdx.x >> 6] = v;
    __syncthreads();
    if (threadIdx.x == 0) blksum[blk] = ws[0] + ws[1] + ws[2] + ws[3];
}

__global__ __launch_bounds__(512) void k_scan_top(int* __restrict__ blksum) {
    __shared__ int sh[512];
    int t = threadIdx.x;
    int seg = t >> 8, j = t & 255;
    int v = (j < SCAN_BLOCKS) ? blksum[seg * SCAN_BLOCKS + j] : 0;
    sh[t] = v;
    __syncthreads();
    for (int off = 1; off < 256; off <<= 1) {
        int u = (j >= off) ? sh[t - off] : 0;
        __syncthreads();
        sh[t] += u;
        __syncthreads();
    }
    if (j < SCAN_BLOCKS) blksum[seg * SCAN_BLOCKS + j] = sh[t] - v;  // exclusive
}

__global__ __launch_bounds__(256) void k_scan_add(const int* __restrict__ cnt0,
                                                  const int* __restrict__ cnt1,
                                                  const int* __restrict__ blksum,
                                                  int* __restrict__ rp0, int* __restrict__ cur0,
                                                  int* __restrict__ rp1, int* __restrict__ cur1,
                                                  float* __restrict__ dis) {
    int blk = blockIdx.x;
    int isB = blk >= SCAN_BLOCKS;
    const int* cnt = isB ? cnt1 : cnt0;
    int lb = isB ? blk - SCAN_BLOCKS : blk;
    int t = threadIdx.x;
    int i = lb * 256 + t;
    int v = (i < N_NODES) ? cnt[i] : 0;
    __shared__ int sh[256];
    sh[t] = v;
    __syncthreads();
    for (int off = 1; off < 256; off <<= 1) {
        int u = (t >= off) ? sh[t - off] : 0;
        __syncthreads();
        sh[t] += u;
        __syncthreads();
    }
    int ex = sh[t] - v + blksum[blk];
    if (i < N_NODES) {
        int* rp = isB ? rp1 : rp0;
        int* cur = isB ? cur1 : cur0;
        rp[i] = ex; cur[i] = ex;
        if (isB) dis[i] = rsqrtf(1.0f + (float)v);
        if (i == N_NODES - 1) rp[N_NODES] = N_EDGES;
    }
}

__global__ void k_scatter(const int* __restrict__ ind0, const int* __restrict__ ind1,
                          const float* __restrict__ vals, const float* __restrict__ dis,
                          int* __restrict__ cur0, int* __restrict__ cur1,
                          int* __restrict__ c0col, float* __restrict__ c0val,
                          int* __restrict__ c1src, float* __restrict__ c1norm) {
    int e = blockIdx.x * blockDim.x + threadIdx.x;
    if (e >= N_EDGES) return;
    int r = ind0[e], c = ind1[e];
    int p0 = atomicAdd(&cur0[r], 1);
    c0col[p0] = c; c0val[p0] = vals[e];
    int p1 = atomicAdd(&cur1[c], 1);
    c1src[p1] = r; c1norm[p1] = dis[r] * dis[c];
}

// ---------------- Chebyshev SpMM (gather): dst[i] = sum_j val*src[col] ----------------
// MODE 0: dst = acc        MODE 1: dst = 2*acc - X   (fused T2 finish)
template<int MODE>
__global__ void k_spmm_gather(const int* __restrict__ rp, const int* __restrict__ col,
                              const float* __restrict__ val, const float* __restrict__ src,
                              const float* __restrict__ X, float* __restrict__ dst) {
    int t = blockIdx.x * blockDim.x + threadIdx.x;
    int node = t >> 6, lane = t & 63;
    if (node >= N_NODES) return;
    int s = rp[node], e = rp[node + 1];
    const float2* s2 = (const float2*)src;
    float2 acc = {0.f, 0.f};
    int j = s;
    for (; j + 3 < e; j += 4) {
        float v0 = val[j], v1 = val[j + 1], v2 = val[j + 2], v3 = val[j + 3];
        float2 p0 = s2[(size_t)col[j]     * 64 + lane];
        float2 p1 = s2[(size_t)col[j + 1] * 64 + lane];
        float2 p2 = s2[(size_t)col[j + 2] * 64 + lane];
        float2 p3 = s2[(size_t)col[j + 3] * 64 + lane];
        acc.x += v0 * p0.x + v1 * p1.x + v2 * p2.x + v3 * p3.x;
        acc.y += v0 * p0.y + v1 * p1.y + v2 * p2.y + v3 * p3.y;
    }
    for (; j < e; ++j) {
        float v = val[j];
        float2 p = s2[(size_t)col[j] * 64 + lane];
        acc.x += v * p.x; acc.y += v * p.y;
    }
    if (MODE == 1) {
        float2 x = ((const float2*)X)[(size_t)node * 64 + lane];
        acc.x = 2.f * acc.x - x.x;
        acc.y = 2.f * acc.y - x.y;
    }
    ((float2*)dst)[(size_t)node * 64 + lane] = acc;
}

// ---------------- LDS-tiled fp32 GEMM: C[M,64] = [s0|s1|s2] @ W ----------------
#define AT_STRIDE 68
template<int RS, int NSEG>
__global__ __launch_bounds__(256) void k_gemm_lds(const float* __restrict__ s0,
                                                  const float* __restrict__ s1,
                                                  const float* __restrict__ s2,
                                                  const float* __restrict__ W,
                                                  float* __restrict__ C) {
    constexpr int CHUNKS = NSEG * RS / 64;
    __shared__ float At[64 * AT_STRIDE];   // A transposed: At[k][row], padded stride
    __shared__ float Wl[64 * 64];          // W chunk as-is: Wl[k][col]
    const int t = threadIdx.x;
    const int l = t & 63, w = t >> 6;
    const int r0 = blockIdx.x * 64;
    const int rbase = w * 16 + (l >> 4) * 4;
    const int cbase = (l & 15) * 4;
    float acc[4][4] = {};

    #pragma unroll
    for (int ch = 0; ch < CHUNKS; ++ch) {
        const float* A = (NSEG == 1) ? s0 : (ch < RS / 64 ? s0 : (ch < 2 * (RS / 64) ? s1 : s2));
        const int koff = (NSEG == 1) ? (ch * 64) : ((ch % (RS / 64)) * 64);
        {
            const float4* Wg = (const float4*)(W + (size_t)ch * 4096);
            #pragma unroll
            for (int i = 0; i < 4; ++i) {
                *(float4*)&Wl[(i * 256 + t) * 4] = Wg[i * 256 + t];
            }
        }
        #pragma unroll
        for (int i = 0; i < 4; ++i) {
            int f   = i * 256 + t;
            int row = f >> 4;
            int kq  = f & 15;
            int gr  = r0 + row; if (gr > N_NODES - 1) gr = N_NODES - 1;
            float4 v = *(const float4*)(A + (size_t)gr * RS + koff + kq * 4);
            At[(kq * 4 + 0) * AT_STRIDE + row] = v.x;
            At[(kq * 4 + 1) * AT_STRIDE + row] = v.y;
            At[(kq * 4 + 2) * AT_STRIDE + row] = v.z;
            At[(kq * 4 + 3) * AT_STRIDE + row] = v.w;
        }
        __syncthreads();
        #pragma unroll 8
        for (int k = 0; k < 64; ++k) {
            float4 a4 = *(const float4*)&At[k * AT_STRIDE + rbase];
            float4 w4 = *(const float4*)&Wl[k * 64 + cbase];
            acc[0][0] += a4.x * w4.x; acc[0][1] += a4.x * w4.y; acc[0][2] += a4.x * w4.z; acc[0][3] += a4.x * w4.w;
            acc[1][0] += a4.y * w4.x; acc[1][1] += a4.y * w4.y; acc[1][2] += a4.y * w4.z; acc[1][3] += a4.y * w4.w;
            acc[2][0] += a4.z * w4.x; acc[2][1] += a4.z * w4.y; acc[2][2] += a4.z * w4.z; acc[2][3] += a4.z * w4.w;
            acc[3][0] += a4.w * w4.x; acc[3][1] += a4.w * w4.y; acc[3][2] += a4.w * w4.z; acc[3][3] += a4.w * w4.w;
        }
        __syncthreads();
    }
    #pragma unroll
    for (int r = 0; r < 4; ++r) {
        int gr = r0 + rbase + r;
        if (gr < N_NODES) {
            float4 o = {acc[r][0], acc[r][1], acc[r][2], acc[r][3]};
            *(float4*)&C[(size_t)gr * 64 + cbase] = o;
        }
    }
}

// ---------------- GCN conv (gather) fused with self-loop + bias + relu ----------------
__global__ void k_conv_gather(const int* __restrict__ rp, const int* __restrict__ src,
                              const float* __restrict__ nrm, const float* __restrict__ h,
                              const float* __restrict__ dis, const float* __restrict__ b,
                              float* __restrict__ x) {
    int t = blockIdx.x * blockDim.x + threadIdx.x;
    int node = t >> 6, lane = t & 63;
    if (node >= N_NODES) return;
    int s = rp[node], e = rp[node + 1];
    float a = 0.f;
    int j = s;
    for (; j + 3 < e; j += 4) {
        float n0 = nrm[j], n1 = nrm[j + 1], n2 = nrm[j + 2], n3 = nrm[j + 3];
        float h0 = h[(size_t)src[j]     * 64 + lane];
        float h1 = h[(size_t)src[j + 1] * 64 + lane];
        float h2 = h[(size_t)src[j + 2] * 64 + lane];
        float h3 = h[(size_t)src[j + 3] * 64 + lane];
        a += n0 * h0 + n1 * h1 + n2 * h2 + n3 * h3;
    }
    for (; j < e; ++j) a += nrm[j] * h[(size_t)src[j] * 64 + lane];
    float d = dis[node];
    a += d * d * h[(size_t)node * 64 + lane] + b[lane];
    x[(size_t)node * 64 + lane] = fmaxf(a, 0.f);
}

// ---------------- pool (batch sorted -> contiguous ranges) + head, 4 waves ----------------
__global__ __launch_bounds__(256) void k_pool_out(const float* __restrict__ x1,
                           const float* __restrict__ x2,
                           const float* __restrict__ x3, const int* __restrict__ batch,
                           const float* __restrict__ Wout, const float* __restrict__ bout,
                           float* __restrict__ out) {
    __shared__ float red[4][64];
    __shared__ float sh[64];
    __shared__ float logits[OUT_DIM];
    int g = blockIdx.x;
    int t = threadIdx.x, f = t & 63, w = t >> 6;
    int lo = 0, hi = N_NODES;
    while (lo < hi) { int m = (lo + hi) >> 1; if (batch[m] < g) lo = m + 1; else hi = m; }
    int start = lo;
    hi = N_NODES;
    while (lo < hi) { int m = (lo + hi) >> 1; if (batch[m] < g + 1) lo = m + 1; else hi = m; }
    int end = lo;
    float a = 0.f;
    for (int i = start + w; i < end; i += 4)
        a += x1[(size_t)i * 64 + f] + x2[(size_t)i * 64 + f] + x3[(size_t)i * 64 + f];
    red[w][f] = a;
    __syncthreads();
    if (w == 0) {
        float cnt = (float)((end - start) > 0 ? (end - start) : 1);
        sh[f] = (red[0][f] + red[1][f] + red[2][f] + red[3][f]) / (3.f * cnt);
    }
    __syncthreads();
    if (t < OUT_DIM) {
        float l = bout[t];
        for (int k = 0; k < 64; ++k) l += sh[k] * Wout[k * OUT_DIM + t];
        logits[t] = l;
    }
    __syncthreads();
    if (t < OUT_DIM) {
        float m = logits[0];
        for (int k = 1; k < OUT_DIM; ++k) m = fmaxf(m, logits[k]);
        float ssum = 0.f;
        for (int k = 0; k < OUT_DIM; ++k) ssum += expf(logits[k] - m);
        out[(size_t)g * OUT_DIM + t] = expf(logits[t] - m) / ssum;
    }
}

extern "C" void kernel_launch(void* const* d_in, const int* in_sizes, int n_in,
                              void* d_out, int out_size, void* d_ws, size_t ws_size,
                              hipStream_t stream) {
    const float* X     = (const float*)d_in[0];
    const int*   Lind  = (const int*)d_in[1];
    const int*   ind0  = Lind;
    const int*   ind1  = Lind + N_EDGES;
    const float* vals  = (const float*)d_in[2];
    const int*   batch = (const int*)d_in[3];
    const float* W1    = (const float*)d_in[4];
    const float* b1    = (const float*)d_in[5];
    const float* W2    = (const float*)d_in[6];
    const float* b2    = (const float*)d_in[7];
    const float* W3    = (const float*)d_in[8];
    const float* b3    = (const float*)d_in[9];
    const float* Wout  = (const float*)d_in[10];
    const float* bout  = (const float*)d_in[11];
    float* out = (float*)d_out;

    // workspace layout (4B words; offsets keep 16B alignment for float4 paths)
    int* deg0   = (int*)d_ws;              // 50000
    int* deg1   = deg0 + 50000;            // 50000
    int* rp0    = deg1 + 50000;            // 50002 (padded)
    int* rp1    = rp0  + 50002;            // 50002 (padded)
    int* cur0   = rp1  + 50002;            // 50000
    int* cur1   = cur0 + 50000;            // 50000
    int* blksum = cur1 + 50000;            // 392 (+pad 8)
    int* c0col  = blksum + 400;            // 800000
    int* c1src  = c0col + 800000;          // 800000
    float* c0val  = (float*)(c1src + 800000);  // 800000
    float* c1norm = c0val + 800000;        // 800000
    float* dis    = c1norm + 800000;       // 50000
    float* T1     = dis + 50000;           // 6,400,000
    float* T2     = T1 + 6400000;
    float* h      = T2 + 6400000;          // 3,200,000
    float* x1     = h  + 3200000;
    float* x2     = x1 + 3200000;
    float* x3     = x2 + 3200000;

    const int B = 256;
    const int edgeGrid = (N_EDGES + B - 1) / B;       // 3125
    const int nodeWaveGrid = (N_NODES * 64) / B;      // 12500
    const int tileGrid = (N_NODES + 63) / 64;         // 782

    // CSR build
    k_zero_int<<<(100000 + B - 1) / B, B, 0, stream>>>(deg0, 100000);  // deg0+deg1 contiguous
    k_hist<<<edgeGrid, B, 0, stream>>>(ind0, ind1, deg0, deg1);
    k_scan_red<<<2 * SCAN_BLOCKS, B, 0, stream>>>(deg0, deg1, blksum);
    k_scan_top<<<1, 512, 0, stream>>>(blksum);
    k_scan_add<<<2 * SCAN_BLOCKS, B, 0, stream>>>(deg0, deg1, blksum,
                                                  rp0, cur0, rp1, cur1, dis);
    k_scatter<<<edgeGrid, B, 0, stream>>>(ind0, ind1, vals, dis, cur0, cur1,
                                          c0col, c0val, c1src, c1norm);

    // Chebyshev: T1 = L X ; T2 = 2 L T1 - X (fused)
    k_spmm_gather<0><<<nodeWaveGrid, B, 0, stream>>>(rp0, c0col, c0val, X,  nullptr, T1);
    k_spmm_gather<1><<<nodeWaveGrid, B, 0, stream>>>(rp0, c0col, c0val, T1, X,       T2);

    // layer 1
    k_gemm_lds<128, 3><<<tileGrid, B, 0, stream>>>(X, T1, T2, W1, h);
    k_conv_gather<<<nodeWaveGrid, B, 0, stream>>>(rp1, c1src, c1norm, h, dis, b1, x1);

    // layer 2
    k_gemm_lds<64, 1><<<tileGrid, B, 0, stream>>>(x1, x1, x1, W2, h);
    k_conv_gather<<<nodeWaveGrid, B, 0, stream>>>(rp1, c1src, c1norm, h, dis, b2, x2);

    // layer 3
    k_gemm_lds<64, 1><<<tileGrid, B, 0, stream>>>(x2, x2, x2, W3, h);
    k_conv_gather<<<nodeWaveGrid, B, 0, stream>>>(rp1, c1src, c1norm, h, dis, b3, x3);

    // pool + head
    k_pool_out<<<N_GRAPHS, B, 0, stream>>>(x1, x2, x3, batch, Wout, bout, out);
}

// Round 6
// 501.192 us; speedup vs baseline: 3.4763x; 1.0745x over previous
//
#include <hip/hip_runtime.h>
#include <hip/hip_bf16.h>

#define N_NODES 50000
#define N_EDGES 800000
#define IN_DIM 128
#define F_SIZE 64
#define N_GRAPHS 512
#define OUT_DIM 10
#define SCAN_BLOCKS 196   // ceil(50000/256)

// ---------------- CSR build ----------------
__global__ void k_zero_int(int* __restrict__ p, int n) {
    int i = blockIdx.x * blockDim.x + threadIdx.x;
    if (i < n) p[i] = 0;
}

__global__ void k_hist(const int* __restrict__ ind0, const int* __restrict__ ind1,
                       int* __restrict__ deg0, int* __restrict__ deg1) {
    int e = blockIdx.x * blockDim.x + threadIdx.x;
    if (e < N_EDGES) {
        atomicAdd(&deg0[ind0[e]], 1);
        atomicAdd(&deg1[ind1[e]], 1);
    }
}

// ---- hierarchical exclusive scan over deg0 (blocks 0..195) and deg1 (196..391) ----
__global__ __launch_bounds__(256) void k_scan_red(const int* __restrict__ cnt0,
                                                  const int* __restrict__ cnt1,
                                                  int* __restrict__ blksum) {
    int blk = blockIdx.x;
    const int* cnt = (blk < SCAN_BLOCKS) ? cnt0 : cnt1;
    int lb = (blk < SCAN_BLOCKS) ? blk : blk - SCAN_BLOCKS;
    int i = lb * 256 + threadIdx.x;
    int v = (i < N_NODES) ? cnt[i] : 0;
    #pragma unroll
    for (int off = 32; off; off >>= 1) v += __shfl_down(v, off, 64);
    __shared__ int ws[4];
    if ((threadIdx.x & 63) == 0) ws[threadIdx.x >> 6] = v;
    __syncthreads();
    if (threadIdx.x == 0) blksum[blk] = ws[0] + ws[1] + ws[2] + ws[3];
}

__global__ __launch_bounds__(512) void k_scan_top(int* __restrict__ blksum) {
    __shared__ int sh[512];
    int t = threadIdx.x;
    int seg = t >> 8, j = t & 255;
    int v = (j < SCAN_BLOCKS) ? blksum[seg * SCAN_BLOCKS + j] : 0;
    sh[t] = v;
    __syncthreads();
    for (int off = 1; off < 256; off <<= 1) {
        int u = (j >= off) ? sh[t - off] : 0;
        __syncthreads();
        sh[t] += u;
        __syncthreads();
    }
    if (j < SCAN_BLOCKS) blksum[seg * SCAN_BLOCKS + j] = sh[t] - v;  // exclusive
}

__global__ __launch_bounds__(256) void k_scan_add(const int* __restrict__ cnt0,
                                                  const int* __restrict__ cnt1,
                                                  const int* __restrict__ blksum,
                                                  int* __restrict__ rp0, int* __restrict__ cur0,
                                                  int* __restrict__ rp1, int* __restrict__ cur1,
                                                  float* __restrict__ dis) {
    int blk = blockIdx.x;
    int isB = blk >= SCAN_BLOCKS;
    const int* cnt = isB ? cnt1 : cnt0;
    int lb = isB ? blk - SCAN_BLOCKS : blk;
    int t = threadIdx.x;
    int i = lb * 256 + t;
    int v = (i < N_NODES) ? cnt[i] : 0;
    __shared__ int sh[256];
    sh[t] = v;
    __syncthreads();
    for (int off = 1; off < 256; off <<= 1) {
        int u = (t >= off) ? sh[t - off] : 0;
        __syncthreads();
        sh[t] += u;
        __syncthreads();
    }
    int ex = sh[t] - v + blksum[blk];
    if (i < N_NODES) {
        int* rp = isB ? rp1 : rp0;
        int* cur = isB ? cur1 : cur0;
        rp[i] = ex; cur[i] = ex;
        if (isB) dis[i] = rsqrtf(1.0f + (float)v);
        if (i == N_NODES - 1) rp[N_NODES] = N_EDGES;
    }
}

// packed payloads: one 8B write per edge per CSR (halves dirty-line count)
__global__ void k_scatter(const int* __restrict__ ind0, const int* __restrict__ ind1,
                          const float* __restrict__ vals, const float* __restrict__ dis,
                          int* __restrict__ cur0, int* __restrict__ cur1,
                          int2* __restrict__ c0pack, int2* __restrict__ c1pack) {
    int e = blockIdx.x * blockDim.x + threadIdx.x;
    if (e >= N_EDGES) return;
    int r = ind0[e], c = ind1[e];
    int p0 = atomicAdd(&cur0[r], 1);
    c0pack[p0] = make_int2(c, __float_as_int(vals[e]));
    int p1 = atomicAdd(&cur1[c], 1);
    c1pack[p1] = make_int2(r, __float_as_int(dis[r] * dis[c]));
}

// ---------------- 64-dim SpMM gather with fused epilogues ----------------
// MODE 0: dst = A[node] + 2*acc            (R = G1 + 2*(L@G2))
// MODE 1: dst = acc + A[node] - Bb[node]   (h = L@R + G0 - G2)
template<int MODE>
__global__ void k_spmm64(const int* __restrict__ rp, const int2* __restrict__ pack,
                         const float* __restrict__ src, const float* __restrict__ A,
                         const float* __restrict__ Bb, float* __restrict__ dst) {
    int t = blockIdx.x * blockDim.x + threadIdx.x;
    int node = t >> 6, lane = t & 63;
    if (node >= N_NODES) return;
    int s = rp[node], e = rp[node + 1];
    float acc = 0.f;
    int j = s;
    for (; j + 3 < e; j += 4) {
        int2 p0 = pack[j], p1 = pack[j + 1], p2 = pack[j + 2], p3 = pack[j + 3];
        float h0 = src[(size_t)p0.x * 64 + lane];
        float h1 = src[(size_t)p1.x * 64 + lane];
        float h2 = src[(size_t)p2.x * 64 + lane];
        float h3 = src[(size_t)p3.x * 64 + lane];
        acc += __int_as_float(p0.y) * h0 + __int_as_float(p1.y) * h1
             + __int_as_float(p2.y) * h2 + __int_as_float(p3.y) * h3;
    }
    for (; j < e; ++j) {
        int2 p = pack[j];
        acc += __int_as_float(p.y) * src[(size_t)p.x * 64 + lane];
    }
    size_t idx = (size_t)node * 64 + lane;
    float o;
    if (MODE == 0) o = A[idx] + 2.f * acc;
    else           o = acc + A[idx] - Bb[idx];
    dst[idx] = o;
}

// ---------------- LDS-tiled fp32 GEMM: C[M,64] = s0 @ W (K = RS) ----------------
#define AT_STRIDE 68
template<int RS>
__global__ __launch_bounds__(256) void k_gemm_lds(const float* __restrict__ s0,
                                                  const float* __restrict__ W,
                                                  float* __restrict__ C) {
    constexpr int CHUNKS = RS / 64;
    __shared__ float At[64 * AT_STRIDE];   // A transposed: At[k][row], padded stride
    __shared__ float Wl[64 * 64];          // W chunk as-is: Wl[k][col]
    const int t = threadIdx.x;
    const int l = t & 63, w = t >> 6;
    const int r0 = blockIdx.x * 64;
    const int rbase = w * 16 + (l >> 4) * 4;
    const int cbase = (l & 15) * 4;
    float acc[4][4] = {};

    #pragma unroll
    for (int ch = 0; ch < CHUNKS; ++ch) {
        const int koff = ch * 64;
        {
            const float4* Wg = (const float4*)(W + (size_t)ch * 4096);
            #pragma unroll
            for (int i = 0; i < 4; ++i) {
                *(float4*)&Wl[(i * 256 + t) * 4] = Wg[i * 256 + t];
            }
        }
        #pragma unroll
        for (int i = 0; i < 4; ++i) {
            int f   = i * 256 + t;
            int row = f >> 4;
            int kq  = f & 15;
            int gr  = r0 + row; if (gr > N_NODES - 1) gr = N_NODES - 1;
            float4 v = *(const float4*)(s0 + (size_t)gr * RS + koff + kq * 4);
            At[(kq * 4 + 0) * AT_STRIDE + row] = v.x;
            At[(kq * 4 + 1) * AT_STRIDE + row] = v.y;
            At[(kq * 4 + 2) * AT_STRIDE + row] = v.z;
            At[(kq * 4 + 3) * AT_STRIDE + row] = v.w;
        }
        __syncthreads();
        #pragma unroll 8
        for (int k = 0; k < 64; ++k) {
            float4 a4 = *(const float4*)&At[k * AT_STRIDE + rbase];
            float4 w4 = *(const float4*)&Wl[k * 64 + cbase];
            acc[0][0] += a4.x * w4.x; acc[0][1] += a4.x * w4.y; acc[0][2] += a4.x * w4.z; acc[0][3] += a4.x * w4.w;
            acc[1][0] += a4.y * w4.x; acc[1][1] += a4.y * w4.y; acc[1][2] += a4.y * w4.z; acc[1][3] += a4.y * w4.w;
            acc[2][0] += a4.z * w4.x; acc[2][1] += a4.z * w4.y; acc[2][2] += a4.z * w4.z; acc[2][3] += a4.z * w4.w;
            acc[3][0] += a4.w * w4.x; acc[3][1] += a4.w * w4.y; acc[3][2] += a4.w * w4.z; acc[3][3] += a4.w * w4.w;
        }
        __syncthreads();
    }
    #pragma unroll
    for (int r = 0; r < 4; ++r) {
        int gr = r0 + rbase + r;
        if (gr < N_NODES) {
            float4 o = {acc[r][0], acc[r][1], acc[r][2], acc[r][3]};
            *(float4*)&C[(size_t)gr * 64 + cbase] = o;
        }
    }
}

// ---------------- GCN conv (gather, packed) + self-loop + bias + relu ----------------
__global__ void k_conv_gather(const int* __restrict__ rp, const int2* __restrict__ pack,
                              const float* __restrict__ h,
                              const float* __restrict__ dis, const float* __restrict__ b,
                              float* __restrict__ x) {
    int t = blockIdx.x * blockDim.x + threadIdx.x;
    int node = t >> 6, lane = t & 63;
    if (node >= N_NODES) return;
    int s = rp[node], e = rp[node + 1];
    float a = 0.f;
    int j = s;
    for (; j + 3 < e; j += 4) {
        int2 p0 = pack[j], p1 = pack[j + 1], p2 = pack[j + 2], p3 = pack[j + 3];
        float h0 = h[(size_t)p0.x * 64 + lane];
        float h1 = h[(size_t)p1.x * 64 + lane];
        float h2 = h[(size_t)p2.x * 64 + lane];
        float h3 = h[(size_t)p3.x * 64 + lane];
        a += __int_as_float(p0.y) * h0 + __int_as_float(p1.y) * h1
           + __int_as_float(p2.y) * h2 + __int_as_float(p3.y) * h3;
    }
    for (; j < e; ++j) {
        int2 p = pack[j];
        a += __int_as_float(p.y) * h[(size_t)p.x * 64 + lane];
    }
    float d = dis[node];
    a += d * d * h[(size_t)node * 64 + lane] + b[lane];
    x[(size_t)node * 64 + lane] = fmaxf(a, 0.f);
}

// ---------------- pool (batch sorted -> contiguous ranges) + head, 4 waves ----------------
__global__ __launch_bounds__(256) void k_pool_out(const float* __restrict__ x1,
                           const float* __restrict__ x2,
                           const float* __restrict__ x3, const int* __restrict__ batch,
                           const float* __restrict__ Wout, const float* __restrict__ bout,
                           float* __restrict__ out) {
    __shared__ float red[4][64];
    __shared__ float sh[64];
    __shared__ float logits[OUT_DIM];
    int g = blockIdx.x;
    int t = threadIdx.x, f = t & 63, w = t >> 6;
    int lo = 0, hi = N_NODES;
    while (lo < hi) { int m = (lo + hi) >> 1; if (batch[m] < g) lo = m + 1; else hi = m; }
    int start = lo;
    hi = N_NODES;
    while (lo < hi) { int m = (lo + hi) >> 1; if (batch[m] < g + 1) lo = m + 1; else hi = m; }
    int end = lo;
    float a = 0.f;
    for (int i = start + w; i < end; i += 4)
        a += x1[(size_t)i * 64 + f] + x2[(size_t)i * 64 + f] + x3[(size_t)i * 64 + f];
    red[w][f] = a;
    __syncthreads();
    if (w == 0) {
        float cnt = (float)((end - start) > 0 ? (end - start) : 1);
        sh[f] = (red[0][f] + red[1][f] + red[2][f] + red[3][f]) / (3.f * cnt);
    }
    __syncthreads();
    if (t < OUT_DIM) {
        float l = bout[t];
        for (int k = 0; k < 64; ++k) l += sh[k] * Wout[k * OUT_DIM + t];
        logits[t] = l;
    }
    __syncthreads();
    if (t < OUT_DIM) {
        float m = logits[0];
        for (int k = 1; k < OUT_DIM; ++k) m = fmaxf(m, logits[k]);
        float ssum = 0.f;
        for (int k = 0; k < OUT_DIM; ++k) ssum += expf(logits[k] - m);
        out[(size_t)g * OUT_DIM + t] = expf(logits[t] - m) / ssum;
    }
}

extern "C" void kernel_launch(void* const* d_in, const int* in_sizes, int n_in,
                              void* d_out, int out_size, void* d_ws, size_t ws_size,
                              hipStream_t stream) {
    const float* X     = (const float*)d_in[0];
    const int*   Lind  = (const int*)d_in[1];
    const int*   ind0  = Lind;
    const int*   ind1  = Lind + N_EDGES;
    const float* vals  = (const float*)d_in[2];
    const int*   batch = (const int*)d_in[3];
    const float* W1    = (const float*)d_in[4];
    const float* b1    = (const float*)d_in[5];
    const float* W2    = (const float*)d_in[6];
    const float* b2    = (const float*)d_in[7];
    const float* W3    = (const float*)d_in[8];
    const float* b3    = (const float*)d_in[9];
    const float* Wout  = (const float*)d_in[10];
    const float* bout  = (const float*)d_in[11];
    float* out = (float*)d_out;

    // workspace layout (4B words; G buffers at %4==0 word offsets -> 16B aligned)
    int* deg0   = (int*)d_ws;              // 50000
    int* deg1   = deg0 + 50000;            // 50000
    int* rp0    = deg1 + 50000;            // 50002
    int* rp1    = rp0  + 50002;            // 50002
    int* cur0   = rp1  + 50002;            // 50000
    int* cur1   = cur0 + 50000;            // 50000
    int* blksum = cur1 + 50000;            // 400 (392 used)
    int2* c0pack = (int2*)(blksum + 400);  // 800000 int2
    int2* c1pack = c0pack + 800000;        // 800000 int2
    float* dis   = (float*)(c1pack + 800000);  // 50000
    float* G0    = dis + 50000;            // 3,200,000  (offset word%4==0)
    float* G1    = G0 + 3200000;
    float* G2    = G1 + 3200000;
    float* R     = G2 + 3200000;
    float* h     = R  + 3200000;
    float* x1    = h  + 3200000;
    float* x2    = x1 + 3200000;
    float* x3    = x2 + 3200000;

    const int B = 256;
    const int edgeGrid = (N_EDGES + B - 1) / B;       // 3125
    const int nodeWaveGrid = (N_NODES * 64) / B;      // 12500
    const int tileGrid = (N_NODES + 63) / 64;         // 782

    // CSR build
    k_zero_int<<<(100000 + B - 1) / B, B, 0, stream>>>(deg0, 100000);  // deg0+deg1 contiguous
    k_hist<<<edgeGrid, B, 0, stream>>>(ind0, ind1, deg0, deg1);
    k_scan_red<<<2 * SCAN_BLOCKS, B, 0, stream>>>(deg0, deg1, blksum);
    k_scan_top<<<1, 512, 0, stream>>>(blksum);
    k_scan_add<<<2 * SCAN_BLOCKS, B, 0, stream>>>(deg0, deg1, blksum,
                                                  rp0, cur0, rp1, cur1, dis);
    k_scatter<<<edgeGrid, B, 0, stream>>>(ind0, ind1, vals, dis, cur0, cur1,
                                          c0pack, c1pack);

    // layer-1 GEMMs: G0 = X@W1[0:128], G1 = X@W1[128:256], G2 = X@W1[256:384]
    k_gemm_lds<128><<<tileGrid, B, 0, stream>>>(X, W1,              G0);
    k_gemm_lds<128><<<tileGrid, B, 0, stream>>>(X, W1 +  128 * 64, G1);
    k_gemm_lds<128><<<tileGrid, B, 0, stream>>>(X, W1 +  256 * 64, G2);

    // Chebyshev via linearity (64-dim spmms):
    // R = G1 + 2*(L@G2);  h = L@R + G0 - G2
    k_spmm64<0><<<nodeWaveGrid, B, 0, stream>>>(rp0, c0pack, G2, G1, nullptr, R);
    k_spmm64<1><<<nodeWaveGrid, B, 0, stream>>>(rp0, c0pack, R,  G0, G2,      h);

    // layer 1 conv
    k_conv_gather<<<nodeWaveGrid, B, 0, stream>>>(rp1, c1pack, h, dis, b1, x1);

    // layer 2
    k_gemm_lds<64><<<tileGrid, B, 0, stream>>>(x1, W2, h);
    k_conv_gather<<<nodeWaveGrid, B, 0, stream>>>(rp1, c1pack, h, dis, b2, x2);

    // layer 3
    k_gemm_lds<64><<<tileGrid, B, 0, stream>>>(x2, W3, h);
    k_conv_gather<<<nodeWaveGrid, B, 0, stream>>>(rp1, c1pack, h, dis, b3, x3);

    // pool + head
    k_pool_out<<<N_GRAPHS, B, 0, stream>>>(x1, x2, x3, batch, Wout, bout, out);
}